// Round 2
// baseline (1894.689 us; speedup 1.0000x reference)
//
#include <hip/hip_runtime.h>
#include <hip/hip_bf16.h>

// HeteroGNN fused pipeline for MI355X.
// Sizes fixed by the problem: N=100000 nodes/type, E=1000000 edges/type, H=64, L=8.
#define NN 100000
#define NE 1000000
#define NH 6400000      // N*H floats per [N,64] buffer

// ---------------- zero scratch counters ----------------
__global__ __launch_bounds__(256) void zero_kernel(int* __restrict__ cnt,
                                                   float* __restrict__ bnacc) {
    int i = blockIdx.x * 256 + threadIdx.x;
    if (i < 3 * NN) cnt[i] = 0;
    if (i < 512) bnacc[i] = 0.f;
}

// ---------------- precompute effective weights ----------------
// Weff layout: [layer][which][64][64], which: 0=Ws_eff(m0) 1=Ws_eff(m1) 2=Ws_eff(m2)
//              3=0.5*(Wd_eff(m1)+Wd_eff(m2)) 4=Wd_eff(m0)
// by1[l][64] = bias for y1;  by0[l][64] = 0.5*(b_eff(m1)+b_eff(m2))
__global__ __launch_bounds__(256) void prep_kernel(
    const float* __restrict__ Wsrc, const float* __restrict__ bsrc,
    const float* __restrict__ Wdst, const float* __restrict__ bdst,
    const float* __restrict__ Wupd, const float* __restrict__ bupd,
    float* __restrict__ Weff, float* __restrict__ by1, float* __restrict__ by0) {
    int t = blockIdx.x * 256 + threadIdx.x;
    if (t < 2 * 5 * 4096) {
        int l = t / 20480;
        int rem = t % 20480;
        int which = rem / 4096;
        int kc = rem % 4096;
        int k = kc >> 6, c = kc & 63;
        float v = 0.f;
        if (which < 3) {
            int m = which;
            const float* ws = Wsrc + (l * 3 + m) * 4096 + k * 64;
            const float* wu = Wupd + (l * 3 + m) * 8192 + 64 * 64 + c;  // bottom half rows
            for (int k2 = 0; k2 < 64; k2++) v = fmaf(ws[k2], wu[k2 * 64], v);
        } else if (which == 3) {
            const float* wd1 = Wdst + (l * 3 + 1) * 4096 + k * 64;
            const float* wu1 = Wupd + (l * 3 + 1) * 8192 + c;           // top half rows
            const float* wd2 = Wdst + (l * 3 + 2) * 4096 + k * 64;
            const float* wu2 = Wupd + (l * 3 + 2) * 8192 + c;
            for (int k2 = 0; k2 < 64; k2++)
                v += 0.5f * (wd1[k2] * wu1[k2 * 64] + wd2[k2] * wu2[k2 * 64]);
        } else {
            const float* wd = Wdst + (l * 3 + 0) * 4096 + k * 64;
            const float* wu = Wupd + (l * 3 + 0) * 8192 + c;
            for (int k2 = 0; k2 < 64; k2++) v = fmaf(wd[k2], wu[k2 * 64], v);
        }
        Weff[t] = v;
        return;
    }
    t -= 2 * 5 * 4096;
    if (t < 128) {  // by1: full b_eff of message type 0
        int l = t >> 6, c = t & 63;
        const float* wu = Wupd + (l * 3 + 0) * 8192;
        float v = bupd[(l * 3 + 0) * 64 + c];
        for (int k = 0; k < 64; k++) {
            v = fmaf(bdst[(l * 3 + 0) * 64 + k], wu[k * 64 + c], v);
            v = fmaf(bsrc[(l * 3 + 0) * 64 + k], wu[(64 + k) * 64 + c], v);
        }
        by1[l * 64 + c] = v;
        return;
    }
    t -= 128;
    if (t < 128) {  // by0 = 0.5*(b_eff(m1)+b_eff(m2))
        int l = t >> 6, c = t & 63;
        float v = 0.f;
        for (int m = 1; m <= 2; m++) {
            const float* wu = Wupd + (l * 3 + m) * 8192;
            float s = bupd[(l * 3 + m) * 64 + c];
            for (int k = 0; k < 64; k++) {
                s = fmaf(bdst[(l * 3 + m) * 64 + k], wu[k * 64 + c], s);
                s = fmaf(bsrc[(l * 3 + m) * 64 + k], wu[(64 + k) * 64 + c], s);
            }
            v += 0.5f * s;
        }
        by0[l * 64 + c] = v;
    }
}

// ---------------- CSR build ----------------
__global__ __launch_bounds__(256) void hist3_kernel(
    const int* __restrict__ e0, const int* __restrict__ e1,
    const int* __restrict__ e2, int* __restrict__ cnt) {
    int i = blockIdx.x * 256 + threadIdx.x;
    if (i >= NE) return;
    int ty = blockIdx.y;
    const int* e = (ty == 0) ? e0 : (ty == 1) ? e1 : e2;
    atomicAdd(&cnt[ty * NN + e[NE + i]], 1);   // e[1][i] = dst
}

__global__ __launch_bounds__(256) void scan1_kernel(const int* __restrict__ cnt,
                                                    int* __restrict__ offs,
                                                    int* __restrict__ bsums, int n) {
    __shared__ int s[256];
    int i = blockIdx.x * 256 + threadIdx.x;
    int v = (i < n) ? cnt[i] : 0;
    s[threadIdx.x] = v;
    __syncthreads();
    for (int d = 1; d < 256; d <<= 1) {
        int tv = (threadIdx.x >= d) ? s[threadIdx.x - d] : 0;
        __syncthreads();
        s[threadIdx.x] += tv;
        __syncthreads();
    }
    if (i < n) offs[i] = s[threadIdx.x] - v;  // exclusive within block
    if (threadIdx.x == 255) bsums[blockIdx.x] = s[255];
}

__global__ __launch_bounds__(256) void scan2_kernel(int* __restrict__ bsums, int nb) {
    __shared__ int s[256];
    __shared__ int carry;
    if (threadIdx.x == 0) carry = 0;
    __syncthreads();
    for (int base = 0; base < nb; base += 256) {
        int i = base + threadIdx.x;
        int v = (i < nb) ? bsums[i] : 0;
        s[threadIdx.x] = v;
        __syncthreads();
        for (int d = 1; d < 256; d <<= 1) {
            int tv = (threadIdx.x >= d) ? s[threadIdx.x - d] : 0;
            __syncthreads();
            s[threadIdx.x] += tv;
            __syncthreads();
        }
        if (i < nb) bsums[i] = s[threadIdx.x] - v + carry;
        __syncthreads();
        if (threadIdx.x == 0) carry += s[255];
        __syncthreads();
    }
}

__global__ __launch_bounds__(256) void scan3_kernel(int* __restrict__ offs,
                                                    const int* __restrict__ bsums,
                                                    int* __restrict__ cursor, int n) {
    int i = blockIdx.x * 256 + threadIdx.x;
    if (i < n) {
        int v = offs[i] + bsums[blockIdx.x];
        offs[i] = v;
        cursor[i] = v;
    }
    if (i == 0) offs[n] = 3 * NE;
}

__global__ __launch_bounds__(256) void scat3_kernel(
    const int* __restrict__ e0, const int* __restrict__ e1,
    const int* __restrict__ e2, int* __restrict__ cursor, int* __restrict__ csr) {
    int i = blockIdx.x * 256 + threadIdx.x;
    if (i >= NE) return;
    int ty = blockIdx.y;
    const int* e = (ty == 0) ? e0 : (ty == 1) ? e1 : e2;
    int pos = atomicAdd(&cursor[ty * NN + e[NE + i]], 1);
    csr[pos] = e[i];   // store src id, segment-sorted by dst
}

// ---------------- 5-way fused GEMM: out[which] = act(A) @ Weff[which] ----------------
// which: 0:T0=x0@Ws0  1:T1=x1@Ws1  2:T2=x0@Ws2  3:D0=x0@(.5(Wd1+Wd2))  4:D1=x1@Wd0
// BN: apply y->y*sc+sh then leaky on load (layer-2 inputs are pre-BN y buffers).
template <bool BN>
__global__ __launch_bounds__(256, 3) void gemm5_kernel(
    const float* __restrict__ x0, const float* __restrict__ x1,
    const float* __restrict__ Weff, const float* __restrict__ ss0,
    const float* __restrict__ ss1, float* __restrict__ Tbase) {
    constexpr int KP = 260;                  // padded k-plane stride (bank spread)
    __shared__ float lw[4096];               // W [64k][64c], 16 KB
    __shared__ float la[32 * KP];            // A-tile phase [32k][256r swizzled], 33 KB
    const int which = blockIdx.y;
    const bool useX1 = (which == 1) || (which == 4);
    const float* __restrict__ A = useX1 ? x1 : x0;
    const float* __restrict__ ss = useX1 ? ss1 : ss0;
    const float* __restrict__ W = Weff + which * 4096;
    float* __restrict__ out = Tbase + (size_t)which * NH;
    const int t = threadIdx.x;
    for (int i = t; i < 1024; i += 256)
        reinterpret_cast<float4*>(lw)[i] = reinterpret_cast<const float4*>(W)[i];
    const int base = blockIdx.x * 256;
    const int kk = t & 31, rh = t >> 5;      // loader coords
    const int cg = t & 7, rr = t >> 3;       // compute: cols cg*8.., rows rr*8..rr*8+7
    float4 accA[8], accB[8];
#pragma unroll
    for (int j = 0; j < 8; j++) {
        accA[j] = make_float4(0.f, 0.f, 0.f, 0.f);
        accB[j] = make_float4(0.f, 0.f, 0.f, 0.f);
    }
    for (int p = 0; p < 2; p++) {            // k-split phases of 32
        const int col = p * 32 + kk;
        float sc = 0.f, sh = 0.f;
        if (BN) { sc = ss[col]; sh = ss[64 + col]; }
        __syncthreads();                     // protect la from previous phase readers
        const int swz = (kk & 3) << 3;
#pragma unroll
        for (int i = 0; i < 32; i++) {
            int r = rh * 32 + i;
            int grow = base + r;
            float v = 0.f;
            if (grow < NN) {
                v = A[(size_t)grow * 64 + col];
                if (BN) { v = fmaf(v, sc, sh); v = (v >= 0.f) ? v : 0.01f * v; }
            }
            la[kk * KP + (r ^ swz)] = v;
        }
        __syncthreads();
#pragma unroll
        for (int k = 0; k < 32; k++) {
            const int astart = k * KP + ((rr * 8) ^ ((k & 3) << 3));
            const float4 a0 = *reinterpret_cast<const float4*>(&la[astart]);
            const float4 a1 = *reinterpret_cast<const float4*>(&la[astart + 4]);
            const float4* w4 = reinterpret_cast<const float4*>(&lw[(p * 32 + k) * 64 + cg * 8]);
            const float4 w0 = w4[0], w1 = w4[1];
            float ar[8] = {a0.x, a0.y, a0.z, a0.w, a1.x, a1.y, a1.z, a1.w};
#pragma unroll
            for (int j = 0; j < 8; j++) {
                accA[j].x = fmaf(ar[j], w0.x, accA[j].x);
                accA[j].y = fmaf(ar[j], w0.y, accA[j].y);
                accA[j].z = fmaf(ar[j], w0.z, accA[j].z);
                accA[j].w = fmaf(ar[j], w0.w, accA[j].w);
                accB[j].x = fmaf(ar[j], w1.x, accB[j].x);
                accB[j].y = fmaf(ar[j], w1.y, accB[j].y);
                accB[j].z = fmaf(ar[j], w1.z, accB[j].z);
                accB[j].w = fmaf(ar[j], w1.w, accB[j].w);
            }
        }
    }
    const int rbase = base + rr * 8;
#pragma unroll
    for (int j = 0; j < 8; j++) {
        int grow = rbase + j;
        if (grow < NN) {
            float4* o = reinterpret_cast<float4*>(out + (size_t)grow * 64 + cg * 8);
            o[0] = accA[j];
            o[1] = accB[j];
        }
    }
}

// ---------------- aggregation (CSR mean-gather) ----------------
__global__ __launch_bounds__(256) void agg_y1_kernel(
    const float* __restrict__ T0, const float* __restrict__ D1,
    const int* __restrict__ offs, const int* __restrict__ csr,
    const float* __restrict__ by, float* __restrict__ y1) {
    int gid = blockIdx.x * 256 + threadIdx.x;
    int row = gid >> 6, lane = gid & 63;
    if (row >= NN) return;
    int o0 = offs[row], o1 = offs[row + 1];
    float s = 0.f;
    for (int j = o0; j < o1; j++) s += T0[(size_t)csr[j] * 64 + lane];
    int d = o1 - o0;
    float inv = 1.f / (float)(d > 1 ? d : 1);
    y1[(size_t)row * 64 + lane] = D1[(size_t)row * 64 + lane] + s * inv + by[lane];
}

__global__ __launch_bounds__(256) void agg_y0_kernel(
    const float* __restrict__ T1, const float* __restrict__ T2,
    const float* __restrict__ D0, const int* __restrict__ offs,
    const int* __restrict__ csr, const float* __restrict__ by,
    float* __restrict__ y0) {
    int gid = blockIdx.x * 256 + threadIdx.x;
    int row = gid >> 6, lane = gid & 63;
    if (row >= NN) return;
    int a0 = offs[NN + row], a1 = offs[NN + row + 1];
    int b0 = offs[2 * NN + row], b1 = offs[2 * NN + row + 1];
    float s1 = 0.f, s2 = 0.f;
    for (int j = a0; j < a1; j++) s1 += T1[(size_t)csr[j] * 64 + lane];
    for (int j = b0; j < b1; j++) s2 += T2[(size_t)csr[j] * 64 + lane];
    int d1 = a1 - a0, d2 = b1 - b0;
    float i1 = 1.f / (float)(d1 > 1 ? d1 : 1);
    float i2 = 1.f / (float)(d2 > 1 ? d2 : 1);
    y0[(size_t)row * 64 + lane] =
        D0[(size_t)row * 64 + lane] + 0.5f * (s1 * i1 + s2 * i2) + by[lane];
}

// ---------------- batch-norm stats ----------------
__global__ __launch_bounds__(256) void bn_stats_kernel(
    const float* __restrict__ y0, const float* __restrict__ y1,
    float* __restrict__ accbase) {
    const float* __restrict__ y = blockIdx.y ? y1 : y0;
    float* __restrict__ acc = accbase + blockIdx.y * 128;
    const int col = threadIdx.x & 63, rg = threadIdx.x >> 6;
    float s = 0.f, q = 0.f;
    for (int r = blockIdx.x * 4 + rg; r < NN; r += 256 * 4) {
        float v = y[(size_t)r * 64 + col];
        s += v;
        q = fmaf(v, v, q);
    }
    __shared__ float ls[4][64], lq[4][64];
    ls[rg][col] = s;
    lq[rg][col] = q;
    __syncthreads();
    if (rg == 0) {
        s = ls[0][col] + ls[1][col] + ls[2][col] + ls[3][col];
        q = lq[0][col] + lq[1][col] + lq[2][col] + lq[3][col];
        atomicAdd(&acc[col], s);
        atomicAdd(&acc[64 + col], q);
    }
}

__global__ void bn_fin_kernel(const float* __restrict__ acc,
                              const float* __restrict__ gamma,
                              const float* __restrict__ beta,
                              float* __restrict__ bnss, int l) {
    int t = threadIdx.x;
    if (t >= 128) return;
    int ty = t >> 6, c = t & 63;
    int idx = l * 2 + ty;
    const float invn = 1.0f / (float)NN;
    float mean = acc[idx * 128 + c] * invn;
    float msq = acc[idx * 128 + 64 + c] * invn;
    float var = msq - mean * mean;
    float rs = 1.0f / sqrtf(var + 1.0f);   // eps = 1.0 per reference
    float scv = rs * gamma[idx * 64 + c];
    bnss[idx * 128 + c] = scv;
    bnss[idx * 128 + 64 + c] = beta[idx * 64 + c] - mean * scv;
}

// ---------------- head: out = leaky(bn(y)) @ Wp + bp ----------------
__global__ __launch_bounds__(256) void head_kernel(
    const float* __restrict__ y0, const float* __restrict__ y1,
    const float* __restrict__ Wp, const float* __restrict__ bp,
    const float* __restrict__ ssb, float* __restrict__ outb) {
    constexpr int KPH = 68;
    __shared__ float lw[512];
    __shared__ float la[64 * KPH];
    const int ty = blockIdx.y;
    const float* __restrict__ A = ty ? y1 : y0;
    const float* __restrict__ ss = ssb + ty * 128;
    float* __restrict__ out = outb + (size_t)ty * (NN * 8);
    const int t = threadIdx.x;
    for (int i = t; i < 512; i += 256) lw[i] = Wp[ty * 512 + i];   // FIXED: was if(t<512)
    const int col = t & 63, rg = t >> 6;
    const float sc = ss[col], sh = ss[64 + col];
    const int base = blockIdx.x * 64;
    const int swz = (col & 3) << 3;
#pragma unroll
    for (int i = 0; i < 16; i++) {
        int r = rg * 16 + i;
        int grow = base + r;
        float v = 0.f;
        if (grow < NN) {
            v = A[(size_t)grow * 64 + col];
            v = fmaf(v, sc, sh);
            v = (v >= 0.f) ? v : 0.01f * v;
        }
        la[col * KPH + (r ^ swz)] = v;
    }
    __syncthreads();
    const int c = t & 7, rp = t >> 3;   // rows rp*2, rp*2+1; col c
    float o0 = 0.f, o1 = 0.f;
#pragma unroll
    for (int k = 0; k < 64; k++) {
        float w = lw[k * 8 + c];
        int pos = k * KPH + ((rp * 2) ^ ((k & 3) << 3));
        o0 = fmaf(la[pos], w, o0);
        o1 = fmaf(la[pos + 1], w, o1);
    }
    float b = bp[ty * 8 + c];
    int g0 = base + rp * 2;
    if (g0 < NN) out[(size_t)g0 * 8 + c] = o0 + b;
    if (g0 + 1 < NN) out[(size_t)(g0 + 1) * 8 + c] = o1 + b;
}

// ---------------- launch ----------------
extern "C" void kernel_launch(void* const* d_in, const int* in_sizes, int n_in,
                              void* d_out, int out_size, void* d_ws, size_t ws_size,
                              hipStream_t stream) {
    const float* x0 = (const float*)d_in[0];
    const float* x1 = (const float*)d_in[1];
    const int* e0 = (const int*)d_in[2];
    const int* e1 = (const int*)d_in[3];
    const int* e2 = (const int*)d_in[4];
    const float* Wsrc = (const float*)d_in[5];
    const float* bsrc = (const float*)d_in[6];
    const float* Wdst = (const float*)d_in[7];
    const float* bdst = (const float*)d_in[8];
    const float* Wupd = (const float*)d_in[9];
    const float* bupd = (const float*)d_in[10];
    const float* gamma = (const float*)d_in[11];
    const float* beta = (const float*)d_in[12];
    const float* Wp = (const float*)d_in[13];
    const float* bp = (const float*)d_in[14];
    float* outp = (float*)d_out;

    // workspace layout (floats; ~195 MB total)
    float* ws = (float*)d_ws;
    float* T0 = ws;                       // 5 GEMM outputs, contiguous (gemm5 indexes which*NH)
    float* T1 = T0 + NH;
    float* T2 = T1 + NH;
    float* D0 = T2 + NH;
    float* D1 = D0 + NH;
    float* y0 = D1 + NH;
    float* y1 = y0 + NH;
    float* Weff = y1 + NH;                // 2*5*4096 = 40960
    float* by1p = Weff + 40960;           // 128
    float* by0p = by1p + 128;             // 128
    float* bnacc = by0p + 128;            // 512
    float* bnss = bnacc + 512;            // 512
    int* cnt = (int*)(bnss + 512);        // 300000
    int* offs = cnt + 300000;             // 300004 (padded, [3N] = 3E sentinel)
    int* cursor = offs + 300004;          // 300000
    int* bsums = cursor + 300000;         // 2048
    int* csr = bsums + 2048;              // 3000000
    (void)in_sizes; (void)n_in; (void)out_size; (void)ws_size;

    // ---- CSR build + weight prep ----
    zero_kernel<<<1172, 256, 0, stream>>>(cnt, bnacc);
    prep_kernel<<<161, 256, 0, stream>>>(Wsrc, bsrc, Wdst, bdst, Wupd, bupd,
                                         Weff, by1p, by0p);
    hist3_kernel<<<dim3(3907, 3), 256, 0, stream>>>(e0, e1, e2, cnt);
    scan1_kernel<<<1172, 256, 0, stream>>>(cnt, offs, bsums, 300000);
    scan2_kernel<<<1, 256, 0, stream>>>(bsums, 1172);
    scan3_kernel<<<1172, 256, 0, stream>>>(offs, bsums, cursor, 300000);
    scat3_kernel<<<dim3(3907, 3), 256, 0, stream>>>(e0, e1, e2, cursor, csr);

    // ---- layer 0 (raw fp32 inputs) ----
    gemm5_kernel<false><<<dim3(391, 5), 256, 0, stream>>>(x0, x1, Weff, nullptr,
                                                          nullptr, T0);
    agg_y1_kernel<<<25000, 256, 0, stream>>>(T0, D1, offs, csr, by1p, y1);
    agg_y0_kernel<<<25000, 256, 0, stream>>>(T1, T2, D0, offs, csr, by0p, y0);
    bn_stats_kernel<<<dim3(256, 2), 256, 0, stream>>>(y0, y1, bnacc);
    bn_fin_kernel<<<1, 128, 0, stream>>>(bnacc, gamma, beta, bnss, 0);

    // ---- layer 1 (BN+leaky fused into GEMM loads) ----
    gemm5_kernel<true><<<dim3(391, 5), 256, 0, stream>>>(y0, y1, Weff + 20480,
                                                         bnss, bnss + 128, T0);
    agg_y1_kernel<<<25000, 256, 0, stream>>>(T0, D1, offs, csr, by1p + 64, y1);
    agg_y0_kernel<<<25000, 256, 0, stream>>>(T1, T2, D0, offs, csr, by0p + 64, y0);
    bn_stats_kernel<<<dim3(256, 2), 256, 0, stream>>>(y0, y1, bnacc + 256);
    bn_fin_kernel<<<1, 128, 0, stream>>>(bnacc, gamma, beta, bnss, 1);

    // ---- heads (BN+leaky fused) ----
    head_kernel<<<dim3(1563, 2), 256, 0, stream>>>(y0, y1, Wp, bp, bnss + 256, outp);
}

// Round 3
// 1137.933 us; speedup vs baseline: 1.6650x; 1.6650x over previous
//
#include <hip/hip_runtime.h>
#include <hip/hip_bf16.h>

// HeteroGNN fused pipeline for MI355X.
// N=100000 nodes/type, E=1000000 edges/type, H=64, L=8.
#define NN 100000
#define NE 1000000
#define NH 6400000      // N*H elements per [N,64] buffer

typedef unsigned int uint;
typedef unsigned short ushort;

// bf16 helpers (RNE), independent of hip_bf16.h API details
static __device__ inline ushort f2bf(float x) {
    uint u = __float_as_uint(x);
    u = u + 0x7fffu + ((u >> 16) & 1u);
    return (ushort)(u >> 16);
}
static __device__ inline float bf2f(uint h) {   // h: low 16 bits hold bf16
    return __uint_as_float(h << 16);
}
static __device__ inline uint pack2(float lo, float hi) {
    return (uint)f2bf(lo) | ((uint)f2bf(hi) << 16);
}

// ---------------- zero scratch counters ----------------
__global__ __launch_bounds__(256) void zero_kernel(int* __restrict__ cnt,
                                                   float* __restrict__ bnacc) {
    int i = blockIdx.x * 256 + threadIdx.x;
    if (i < 3 * NN) cnt[i] = 0;
    if (i < 512) bnacc[i] = 0.f;
}

// ---------------- precompute effective weights ----------------
// Weff layout: [layer][which][64][64], which: 0=Ws_eff(m0) 1=Ws_eff(m1) 2=Ws_eff(m2)
//              3=0.5*(Wd_eff(m1)+Wd_eff(m2)) 4=Wd_eff(m0)
__global__ __launch_bounds__(256) void prep_kernel(
    const float* __restrict__ Wsrc, const float* __restrict__ bsrc,
    const float* __restrict__ Wdst, const float* __restrict__ bdst,
    const float* __restrict__ Wupd, const float* __restrict__ bupd,
    float* __restrict__ Weff, float* __restrict__ by1, float* __restrict__ by0) {
    int t = blockIdx.x * 256 + threadIdx.x;
    if (t < 2 * 5 * 4096) {
        int l = t / 20480;
        int rem = t % 20480;
        int which = rem / 4096;
        int kc = rem % 4096;
        int k = kc >> 6, c = kc & 63;
        float v = 0.f;
        if (which < 3) {
            int m = which;
            const float* ws = Wsrc + (l * 3 + m) * 4096 + k * 64;
            const float* wu = Wupd + (l * 3 + m) * 8192 + 64 * 64 + c;  // bottom half rows
            for (int k2 = 0; k2 < 64; k2++) v = fmaf(ws[k2], wu[k2 * 64], v);
        } else if (which == 3) {
            const float* wd1 = Wdst + (l * 3 + 1) * 4096 + k * 64;
            const float* wu1 = Wupd + (l * 3 + 1) * 8192 + c;           // top half rows
            const float* wd2 = Wdst + (l * 3 + 2) * 4096 + k * 64;
            const float* wu2 = Wupd + (l * 3 + 2) * 8192 + c;
            for (int k2 = 0; k2 < 64; k2++)
                v += 0.5f * (wd1[k2] * wu1[k2 * 64] + wd2[k2] * wu2[k2 * 64]);
        } else {
            const float* wd = Wdst + (l * 3 + 0) * 4096 + k * 64;
            const float* wu = Wupd + (l * 3 + 0) * 8192 + c;
            for (int k2 = 0; k2 < 64; k2++) v = fmaf(wd[k2], wu[k2 * 64], v);
        }
        Weff[t] = v;
        return;
    }
    t -= 2 * 5 * 4096;
    if (t < 128) {  // by1: full b_eff of message type 0
        int l = t >> 6, c = t & 63;
        const float* wu = Wupd + (l * 3 + 0) * 8192;
        float v = bupd[(l * 3 + 0) * 64 + c];
        for (int k = 0; k < 64; k++) {
            v = fmaf(bdst[(l * 3 + 0) * 64 + k], wu[k * 64 + c], v);
            v = fmaf(bsrc[(l * 3 + 0) * 64 + k], wu[(64 + k) * 64 + c], v);
        }
        by1[l * 64 + c] = v;
        return;
    }
    t -= 128;
    if (t < 128) {  // by0 = 0.5*(b_eff(m1)+b_eff(m2))
        int l = t >> 6, c = t & 63;
        float v = 0.f;
        for (int m = 1; m <= 2; m++) {
            const float* wu = Wupd + (l * 3 + m) * 8192;
            float s = bupd[(l * 3 + m) * 64 + c];
            for (int k = 0; k < 64; k++) {
                s = fmaf(bdst[(l * 3 + m) * 64 + k], wu[k * 64 + c], s);
                s = fmaf(bsrc[(l * 3 + m) * 64 + k], wu[(64 + k) * 64 + c], s);
            }
            v += 0.5f * s;
        }
        by0[l * 64 + c] = v;
    }
}

// ---------------- CSR build ----------------
__global__ __launch_bounds__(256) void hist3_kernel(
    const int* __restrict__ e0, const int* __restrict__ e1,
    const int* __restrict__ e2, int* __restrict__ cnt) {
    int i = blockIdx.x * 256 + threadIdx.x;
    if (i >= NE) return;
    int ty = blockIdx.y;
    const int* e = (ty == 0) ? e0 : (ty == 1) ? e1 : e2;
    atomicAdd(&cnt[ty * NN + e[NE + i]], 1);   // e[1][i] = dst
}

__global__ __launch_bounds__(256) void scan1_kernel(const int* __restrict__ cnt,
                                                    int* __restrict__ offs,
                                                    int* __restrict__ bsums, int n) {
    __shared__ int s[256];
    int i = blockIdx.x * 256 + threadIdx.x;
    int v = (i < n) ? cnt[i] : 0;
    s[threadIdx.x] = v;
    __syncthreads();
    for (int d = 1; d < 256; d <<= 1) {
        int tv = (threadIdx.x >= d) ? s[threadIdx.x - d] : 0;
        __syncthreads();
        s[threadIdx.x] += tv;
        __syncthreads();
    }
    if (i < n) offs[i] = s[threadIdx.x] - v;  // exclusive within block
    if (threadIdx.x == 255) bsums[blockIdx.x] = s[255];
}

__global__ __launch_bounds__(256) void scan2_kernel(int* __restrict__ bsums, int nb) {
    __shared__ int s[256];
    __shared__ int carry;
    if (threadIdx.x == 0) carry = 0;
    __syncthreads();
    for (int base = 0; base < nb; base += 256) {
        int i = base + threadIdx.x;
        int v = (i < nb) ? bsums[i] : 0;
        s[threadIdx.x] = v;
        __syncthreads();
        for (int d = 1; d < 256; d <<= 1) {
            int tv = (threadIdx.x >= d) ? s[threadIdx.x - d] : 0;
            __syncthreads();
            s[threadIdx.x] += tv;
            __syncthreads();
        }
        if (i < nb) bsums[i] = s[threadIdx.x] - v + carry;
        __syncthreads();
        if (threadIdx.x == 0) carry += s[255];
        __syncthreads();
    }
}

__global__ __launch_bounds__(256) void scan3_kernel(int* __restrict__ offs,
                                                    const int* __restrict__ bsums,
                                                    int* __restrict__ cursor, int n) {
    int i = blockIdx.x * 256 + threadIdx.x;
    if (i < n) {
        int v = offs[i] + bsums[blockIdx.x];
        offs[i] = v;
        cursor[i] = v;
    }
    if (i == 0) offs[n] = 3 * NE;
}

__global__ __launch_bounds__(256) void scat3_kernel(
    const int* __restrict__ e0, const int* __restrict__ e1,
    const int* __restrict__ e2, int* __restrict__ cursor, int* __restrict__ csr) {
    int i = blockIdx.x * 256 + threadIdx.x;
    if (i >= NE) return;
    int ty = blockIdx.y;
    const int* e = (ty == 0) ? e0 : (ty == 1) ? e1 : e2;
    int pos = atomicAdd(&cursor[ty * NN + e[NE + i]], 1);
    csr[pos] = e[i];   // store src id, segment-sorted by dst
}

// ---------------- fused multi-output GEMM ----------------
// grid (782, 2). ty=0: A = x0-type, outputs which {0,2,3}; ty=1: A = x1-type, {1,4}.
// A-tile staged ONCE in LDS (row-major [128][65], conflict-free), reused for all
// consumer W's. W read from global (16 KB, L1-resident). Outputs stored bf16 with
// full-cache-line store instructions (8 lanes x 16B = 128B row).
template <bool BN>
__global__ __launch_bounds__(256) void gemmA_kernel(
    const float* __restrict__ x0, const float* __restrict__ x1,
    const float* __restrict__ Weff, const float* __restrict__ ss0,
    const float* __restrict__ ss1, uint* __restrict__ Tb) {
    __shared__ float la[128 * 65];
    const int ty = blockIdx.y;
    const float* __restrict__ A = ty ? x1 : x0;
    const float* __restrict__ ss = ty ? ss1 : ss0;
    const int t = threadIdx.x;
    const int base = blockIdx.x * 128;
    // ---- loader: 8 float4 chunks per thread, coalesced ----
#pragma unroll
    for (int i = 0; i < 8; i++) {
        int chunk = i * 256 + t;
        int r = chunk >> 4, c4 = chunk & 15;
        int grow = base + r;
        float4 v = make_float4(0.f, 0.f, 0.f, 0.f);
        if (grow < NN)
            v = *reinterpret_cast<const float4*>(A + (size_t)grow * 64 + c4 * 4);
        if (BN) {
            float4 sc = *reinterpret_cast<const float4*>(ss + c4 * 4);
            float4 sh = *reinterpret_cast<const float4*>(ss + 64 + c4 * 4);
            v.x = fmaf(v.x, sc.x, sh.x); v.x = v.x >= 0.f ? v.x : 0.01f * v.x;
            v.y = fmaf(v.y, sc.y, sh.y); v.y = v.y >= 0.f ? v.y : 0.01f * v.y;
            v.z = fmaf(v.z, sc.z, sh.z); v.z = v.z >= 0.f ? v.z : 0.01f * v.z;
            v.w = fmaf(v.w, sc.w, sh.w); v.w = v.w >= 0.f ? v.w : 0.01f * v.w;
        }
        int lb = r * 65 + c4 * 4;
        la[lb] = v.x; la[lb + 1] = v.y; la[lb + 2] = v.z; la[lb + 3] = v.w;
    }
    __syncthreads();
    // ---- compute: thread = 4 rows x 8 cols ----
    const int cg = t & 7, rr = t >> 3;           // rr in 0..31
    const int rb = rr * 4 * 65;
    const int nout = ty ? 2 : 3;
#pragma unroll
    for (int o = 0; o < 3; o++) {
        if (o >= nout) break;
        const int which = ty ? (o == 0 ? 1 : 4) : (o == 0 ? 0 : (o == 1 ? 2 : 3));
        const float* __restrict__ W = Weff + which * 4096;
        float4 a0c[4], a1c[4];                    // 4 rows x (2 x float4 cols)
#pragma unroll
        for (int j = 0; j < 4; j++) {
            a0c[j] = make_float4(0.f, 0.f, 0.f, 0.f);
            a1c[j] = make_float4(0.f, 0.f, 0.f, 0.f);
        }
#pragma unroll 8
        for (int k = 0; k < 64; k++) {
            float a0 = la[rb + k];
            float a1 = la[rb + 65 + k];
            float a2 = la[rb + 130 + k];
            float a3 = la[rb + 195 + k];
            const float4* w4 = reinterpret_cast<const float4*>(W + k * 64 + cg * 8);
            float4 w0 = w4[0], w1 = w4[1];
            a0c[0].x = fmaf(a0, w0.x, a0c[0].x); a0c[0].y = fmaf(a0, w0.y, a0c[0].y);
            a0c[0].z = fmaf(a0, w0.z, a0c[0].z); a0c[0].w = fmaf(a0, w0.w, a0c[0].w);
            a1c[0].x = fmaf(a0, w1.x, a1c[0].x); a1c[0].y = fmaf(a0, w1.y, a1c[0].y);
            a1c[0].z = fmaf(a0, w1.z, a1c[0].z); a1c[0].w = fmaf(a0, w1.w, a1c[0].w);
            a0c[1].x = fmaf(a1, w0.x, a0c[1].x); a0c[1].y = fmaf(a1, w0.y, a0c[1].y);
            a0c[1].z = fmaf(a1, w0.z, a0c[1].z); a0c[1].w = fmaf(a1, w0.w, a0c[1].w);
            a1c[1].x = fmaf(a1, w1.x, a1c[1].x); a1c[1].y = fmaf(a1, w1.y, a1c[1].y);
            a1c[1].z = fmaf(a1, w1.z, a1c[1].z); a1c[1].w = fmaf(a1, w1.w, a1c[1].w);
            a0c[2].x = fmaf(a2, w0.x, a0c[2].x); a0c[2].y = fmaf(a2, w0.y, a0c[2].y);
            a0c[2].z = fmaf(a2, w0.z, a0c[2].z); a0c[2].w = fmaf(a2, w0.w, a0c[2].w);
            a1c[2].x = fmaf(a2, w1.x, a1c[2].x); a1c[2].y = fmaf(a2, w1.y, a1c[2].y);
            a1c[2].z = fmaf(a2, w1.z, a1c[2].z); a1c[2].w = fmaf(a2, w1.w, a1c[2].w);
            a0c[3].x = fmaf(a3, w0.x, a0c[3].x); a0c[3].y = fmaf(a3, w0.y, a0c[3].y);
            a0c[3].z = fmaf(a3, w0.z, a0c[3].z); a0c[3].w = fmaf(a3, w0.w, a0c[3].w);
            a1c[3].x = fmaf(a3, w1.x, a1c[3].x); a1c[3].y = fmaf(a3, w1.y, a1c[3].y);
            a1c[3].z = fmaf(a3, w1.z, a1c[3].z); a1c[3].w = fmaf(a3, w1.w, a1c[3].w);
        }
        // store 4 rows x 8 cols as bf16 (16B per lane per row; lanes cover 128B row)
        uint* __restrict__ out = Tb + (size_t)which * (NH / 2);
#pragma unroll
        for (int j = 0; j < 4; j++) {
            int grow = base + rr * 4 + j;
            if (grow < NN) {
                uint4 pk;
                pk.x = pack2(a0c[j].x, a0c[j].y);
                pk.y = pack2(a0c[j].z, a0c[j].w);
                pk.z = pack2(a1c[j].x, a1c[j].y);
                pk.w = pack2(a1c[j].z, a1c[j].w);
                *reinterpret_cast<uint4*>(out + (size_t)grow * 32 + cg * 4) = pk;
            }
        }
    }
}

// ---------------- aggregation (CSR mean-gather, bf16 T/D, fp32 y out) ----------------
// thread = 2 cols; 32 lanes cover a row (wave handles 2 rows).
__global__ __launch_bounds__(256) void agg_y1_kernel(
    const uint* __restrict__ T0, const uint* __restrict__ D1,
    const int* __restrict__ offs, const int* __restrict__ csr,
    const float* __restrict__ by, float* __restrict__ y1) {
    int gid = blockIdx.x * 256 + threadIdx.x;
    int row = gid >> 5, lane = gid & 31;
    if (row >= NN) return;
    int o0 = offs[row], o1 = offs[row + 1];
    float s0 = 0.f, s1 = 0.f;
    for (int j = o0; j < o1; j++) {
        uint u = T0[(size_t)csr[j] * 32 + lane];
        s0 += bf2f(u & 0xffffu);
        s1 += bf2f(u >> 16);
    }
    int d = o1 - o0;
    float inv = 1.f / (float)(d > 1 ? d : 1);
    uint dd = D1[(size_t)row * 32 + lane];
    float* yr = y1 + (size_t)row * 64 + lane * 2;
    yr[0] = bf2f(dd & 0xffffu) + s0 * inv + by[lane * 2];
    yr[1] = bf2f(dd >> 16) + s1 * inv + by[lane * 2 + 1];
}

__global__ __launch_bounds__(256) void agg_y0_kernel(
    const uint* __restrict__ T1, const uint* __restrict__ T2,
    const uint* __restrict__ D0, const int* __restrict__ offs,
    const int* __restrict__ csr, const float* __restrict__ by,
    float* __restrict__ y0) {
    int gid = blockIdx.x * 256 + threadIdx.x;
    int row = gid >> 5, lane = gid & 31;
    if (row >= NN) return;
    int a0 = offs[NN + row], a1 = offs[NN + row + 1];
    int b0 = offs[2 * NN + row], b1 = offs[2 * NN + row + 1];
    float s10 = 0.f, s11 = 0.f, s20 = 0.f, s21 = 0.f;
    for (int j = a0; j < a1; j++) {
        uint u = T1[(size_t)csr[j] * 32 + lane];
        s10 += bf2f(u & 0xffffu);
        s11 += bf2f(u >> 16);
    }
    for (int j = b0; j < b1; j++) {
        uint u = T2[(size_t)csr[j] * 32 + lane];
        s20 += bf2f(u & 0xffffu);
        s21 += bf2f(u >> 16);
    }
    int d1 = a1 - a0, d2 = b1 - b0;
    float i1 = 1.f / (float)(d1 > 1 ? d1 : 1);
    float i2 = 1.f / (float)(d2 > 1 ? d2 : 1);
    uint dd = D0[(size_t)row * 32 + lane];
    float* yr = y0 + (size_t)row * 64 + lane * 2;
    yr[0] = bf2f(dd & 0xffffu) + 0.5f * (s10 * i1 + s20 * i2) + by[lane * 2];
    yr[1] = bf2f(dd >> 16) + 0.5f * (s11 * i1 + s21 * i2) + by[lane * 2 + 1];
}

// ---------------- batch-norm stats ----------------
__global__ __launch_bounds__(256) void bn_stats_kernel(
    const float* __restrict__ y0, const float* __restrict__ y1,
    float* __restrict__ accbase) {
    const float* __restrict__ y = blockIdx.y ? y1 : y0;
    float* __restrict__ acc = accbase + blockIdx.y * 128;
    const int col = threadIdx.x & 63, rg = threadIdx.x >> 6;
    float s = 0.f, q = 0.f;
    for (int r = blockIdx.x * 4 + rg; r < NN; r += 256 * 4) {
        float v = y[(size_t)r * 64 + col];
        s += v;
        q = fmaf(v, v, q);
    }
    __shared__ float ls[4][64], lq[4][64];
    ls[rg][col] = s;
    lq[rg][col] = q;
    __syncthreads();
    if (rg == 0) {
        s = ls[0][col] + ls[1][col] + ls[2][col] + ls[3][col];
        q = lq[0][col] + lq[1][col] + lq[2][col] + lq[3][col];
        atomicAdd(&acc[col], s);
        atomicAdd(&acc[64 + col], q);
    }
}

__global__ void bn_fin_kernel(const float* __restrict__ acc,
                              const float* __restrict__ gamma,
                              const float* __restrict__ beta,
                              float* __restrict__ bnss, int l) {
    int t = threadIdx.x;
    if (t >= 128) return;
    int ty = t >> 6, c = t & 63;
    int idx = l * 2 + ty;
    const float invn = 1.0f / (float)NN;
    float mean = acc[idx * 128 + c] * invn;
    float msq = acc[idx * 128 + 64 + c] * invn;
    float var = msq - mean * mean;
    float rs = 1.0f / sqrtf(var + 1.0f);   // eps = 1.0 per reference
    float scv = rs * gamma[idx * 64 + c];
    bnss[idx * 128 + c] = scv;
    bnss[idx * 128 + 64 + c] = beta[idx * 64 + c] - mean * scv;
}

// ---------------- head: out = leaky(bn(y)) @ Wp + bp ----------------
__global__ __launch_bounds__(256) void head_kernel(
    const float* __restrict__ y0, const float* __restrict__ y1,
    const float* __restrict__ Wp, const float* __restrict__ bp,
    const float* __restrict__ ssb, float* __restrict__ outb) {
    constexpr int KPH = 68;
    __shared__ float lw[512];
    __shared__ float la[64 * KPH];
    const int ty = blockIdx.y;
    const float* __restrict__ A = ty ? y1 : y0;
    const float* __restrict__ ss = ssb + ty * 128;
    float* __restrict__ out = outb + (size_t)ty * (NN * 8);
    const int t = threadIdx.x;
    for (int i = t; i < 512; i += 256) lw[i] = Wp[ty * 512 + i];
    const int col = t & 63, rg = t >> 6;
    const float sc = ss[col], sh = ss[64 + col];
    const int base = blockIdx.x * 64;
    const int swz = (col & 3) << 3;
#pragma unroll
    for (int i = 0; i < 16; i++) {
        int r = rg * 16 + i;
        int grow = base + r;
        float v = 0.f;
        if (grow < NN) {
            v = A[(size_t)grow * 64 + col];
            v = fmaf(v, sc, sh);
            v = (v >= 0.f) ? v : 0.01f * v;
        }
        la[col * KPH + (r ^ swz)] = v;
    }
    __syncthreads();
    const int c = t & 7, rp = t >> 3;   // rows rp*2, rp*2+1; col c
    float o0 = 0.f, o1 = 0.f;
#pragma unroll
    for (int k = 0; k < 64; k++) {
        float w = lw[k * 8 + c];
        int pos = k * KPH + ((rp * 2) ^ ((k & 3) << 3));
        o0 = fmaf(la[pos], w, o0);
        o1 = fmaf(la[pos + 1], w, o1);
    }
    float b = bp[ty * 8 + c];
    int g0 = base + rp * 2;
    if (g0 < NN) out[(size_t)g0 * 8 + c] = o0 + b;
    if (g0 + 1 < NN) out[(size_t)(g0 + 1) * 8 + c] = o1 + b;
}

// ---------------- launch ----------------
extern "C" void kernel_launch(void* const* d_in, const int* in_sizes, int n_in,
                              void* d_out, int out_size, void* d_ws, size_t ws_size,
                              hipStream_t stream) {
    const float* x0 = (const float*)d_in[0];
    const float* x1 = (const float*)d_in[1];
    const int* e0 = (const int*)d_in[2];
    const int* e1 = (const int*)d_in[3];
    const int* e2 = (const int*)d_in[4];
    const float* Wsrc = (const float*)d_in[5];
    const float* bsrc = (const float*)d_in[6];
    const float* Wdst = (const float*)d_in[7];
    const float* bdst = (const float*)d_in[8];
    const float* Wupd = (const float*)d_in[9];
    const float* bupd = (const float*)d_in[10];
    const float* gamma = (const float*)d_in[11];
    const float* beta = (const float*)d_in[12];
    const float* Wp = (const float*)d_in[13];
    const float* bp = (const float*)d_in[14];
    float* outp = (float*)d_out;

    // workspace layout (~131 MB)
    uint* Tb = (uint*)d_ws;               // 5 bf16 buffers [N,64]: 5*NH/2 uints = 64 MB
    float* y0 = (float*)(Tb + 5 * (NH / 2));
    float* y1 = y0 + NH;
    float* Weff = y1 + NH;                // 2*5*4096 = 40960
    float* by1p = Weff + 40960;           // 128
    float* by0p = by1p + 128;             // 128
    float* bnacc = by0p + 128;            // 512
    float* bnss = bnacc + 512;            // 512
    int* cnt = (int*)(bnss + 512);        // 300000
    int* offs = cnt + 300000;             // 300004
    int* cursor = offs + 300004;          // 300000
    int* bsums = cursor + 300000;         // 2048
    int* csr = bsums + 2048;              // 3000000
    (void)in_sizes; (void)n_in; (void)out_size; (void)ws_size;

    const uint* T0 = Tb;
    const uint* T1 = Tb + 1 * (NH / 2);
    const uint* T2 = Tb + 2 * (NH / 2);
    const uint* D0 = Tb + 3 * (NH / 2);
    const uint* D1 = Tb + 4 * (NH / 2);

    // ---- CSR build + weight prep ----
    zero_kernel<<<1172, 256, 0, stream>>>(cnt, bnacc);
    prep_kernel<<<161, 256, 0, stream>>>(Wsrc, bsrc, Wdst, bdst, Wupd, bupd,
                                         Weff, by1p, by0p);
    hist3_kernel<<<dim3(3907, 3), 256, 0, stream>>>(e0, e1, e2, cnt);
    scan1_kernel<<<1172, 256, 0, stream>>>(cnt, offs, bsums, 300000);
    scan2_kernel<<<1, 256, 0, stream>>>(bsums, 1172);
    scan3_kernel<<<1172, 256, 0, stream>>>(offs, bsums, cursor, 300000);
    scat3_kernel<<<dim3(3907, 3), 256, 0, stream>>>(e0, e1, e2, cursor, csr);

    // ---- layer 0 ----
    gemmA_kernel<false><<<dim3(782, 2), 256, 0, stream>>>(x0, x1, Weff, nullptr,
                                                          nullptr, Tb);
    agg_y1_kernel<<<12500, 256, 0, stream>>>(T0, D1, offs, csr, by1p, y1);
    agg_y0_kernel<<<12500, 256, 0, stream>>>(T1, T2, D0, offs, csr, by0p, y0);
    bn_stats_kernel<<<dim3(256, 2), 256, 0, stream>>>(y0, y1, bnacc);
    bn_fin_kernel<<<1, 128, 0, stream>>>(bnacc, gamma, beta, bnss, 0);

    // ---- layer 1 (BN+leaky fused into GEMM loads) ----
    gemmA_kernel<true><<<dim3(782, 2), 256, 0, stream>>>(y0, y1, Weff + 20480,
                                                         bnss, bnss + 128, Tb);
    agg_y1_kernel<<<12500, 256, 0, stream>>>(T0, D1, offs, csr, by1p + 64, y1);
    agg_y0_kernel<<<12500, 256, 0, stream>>>(T1, T2, D0, offs, csr, by0p + 64, y0);
    bn_stats_kernel<<<dim3(256, 2), 256, 0, stream>>>(y0, y1, bnacc + 256);
    bn_fin_kernel<<<1, 128, 0, stream>>>(bnacc, gamma, beta, bnss, 1);

    // ---- heads (BN+leaky fused) ----
    head_kernel<<<dim3(1563, 2), 256, 0, stream>>>(y0, y1, Wp, bp, bnss + 256, outp);
}